// Round 1
// baseline (344.976 us; speedup 1.0000x reference)
//
#include <hip/hip_runtime.h>
#include <math.h>

// RG-LRU: B=4, T=4096, W=1024, H=8, BW=128
#define NB 4
#define NT 4096
#define NW 1024
#define NH 8
#define NBW 128
#define ROWS 32            // rows (b,t) per block tile in gates kernel
#define KT 32              // k-tile for LDS staging
#define CHUNK 64           // scan chunk length
#define NCH (NT/CHUNK)     // 64 chunks

__device__ __forceinline__ float sigmoidf_(float z) { return 1.0f / (1.0f + expf(-z)); }

// ---------------- K1: block-diagonal matvecs + gates + elementwise ----------------
// grid: (NH, NB*NT/ROWS), block 256.
// Thread tile: 4 rows x 4 cols, both gates (32 fp32 accumulators).
// Writes a_eff (reset folded in) to ws, normed_x to d_out.
__global__ __launch_bounds__(256)
void gates_kernel(const float* __restrict__ x, const int* __restrict__ seg,
                  const float* __restrict__ a_param,
                  const float* __restrict__ w_in, const float* __restrict__ b_in,
                  const float* __restrict__ w_a,  const float* __restrict__ b_a,
                  float* __restrict__ a_eff, float* __restrict__ normed)
{
    __shared__ float sWin[KT][NBW];       // 16 KB
    __shared__ float sWa [KT][NBW];       // 16 KB
    __shared__ float sXT [KT][ROWS + 4];  // 4.5 KB, pad=4 keeps 16B alignment, x transposed

    const int h    = blockIdx.x;
    const int row0 = blockIdx.y * ROWS;
    const int tid  = threadIdx.x;
    const int jc = tid & 31, rc = tid >> 5;
    const int j0 = jc * 4, r0 = rc * 4;

    float accx[4][4] = {{0.f}};
    float acca[4][4] = {{0.f}};

    for (int kt = 0; kt < NBW; kt += KT) {
        // stage W slices (coalesced float4)
        const float4* pin = (const float4*)(w_in + ((size_t)h * NBW + kt) * NBW);
        const float4* pa  = (const float4*)(w_a  + ((size_t)h * NBW + kt) * NBW);
        float4* s4i = (float4*)&sWin[0][0];
        float4* s4a = (float4*)&sWa[0][0];
        #pragma unroll
        for (int k = tid; k < KT * NBW / 4; k += 256) { s4i[k] = pin[k]; s4a[k] = pa[k]; }
        // stage x slice transposed: sXT[i][r] = x[row0+r][h*128 + kt + i]
        {
            const int i = tid & 31, rr0 = tid >> 5;
            #pragma unroll
            for (int rr = rr0; rr < ROWS; rr += 8)
                sXT[i][rr] = x[(size_t)(row0 + rr) * NW + h * NBW + kt + i];
        }
        __syncthreads();
        #pragma unroll
        for (int i = 0; i < KT; ++i) {
            const float4 xv = *(const float4*)&sXT[i][r0];   // broadcast within half-wave
            const float4 wi = *(const float4*)&sWin[i][j0];
            const float4 wa = *(const float4*)&sWa[i][j0];
            const float xr[4]  = {xv.x, xv.y, xv.z, xv.w};
            const float wiv[4] = {wi.x, wi.y, wi.z, wi.w};
            const float wav[4] = {wa.x, wa.y, wa.z, wa.w};
            #pragma unroll
            for (int r = 0; r < 4; ++r)
                #pragma unroll
                for (int j = 0; j < 4; ++j) {
                    accx[r][j] = fmaf(xr[r], wiv[j], accx[r][j]);
                    acca[r][j] = fmaf(xr[r], wav[j], acca[r][j]);
                }
        }
        __syncthreads();
    }

    // epilogue: gates, log_a, multiplier, reset fold
    float bi[4], ba[4], sp[4];
    #pragma unroll
    for (int j = 0; j < 4; ++j) {
        const int col = h * NBW + j0 + j;
        bi[j] = b_in[col];
        ba[j] = b_a[col];
        sp[j] = log1pf(expf(a_param[col]));  // softplus; a_param < 0 so no overflow
    }
    #pragma unroll
    for (int r = 0; r < 4; ++r) {
        const int row = row0 + r0 + r;
        const bool reset = (seg[row] == 0);
        const float4 xv = *(const float4*)&x[(size_t)row * NW + h * NBW + j0];
        const float xr[4] = {xv.x, xv.y, xv.z, xv.w};
        float4 on, oa;
        float* pn  = (float*)&on;
        float* poa = (float*)&oa;
        #pragma unroll
        for (int j = 0; j < 4; ++j) {
            const float gx    = sigmoidf_(accx[r][j] + bi[j]);
            const float ga    = sigmoidf_(acca[r][j] + ba[j]);
            const float log_a = -8.0f * ga * sp[j];
            const float a     = expf(log_a);
            const float mult  = sqrtf(fmaxf(1.0f - expf(2.0f * log_a), 0.0f));
            pn[j]  = xr[j] * gx * mult;
            poa[j] = reset ? 0.0f : a;
        }
        const size_t o = (size_t)row * NW + h * NBW + j0;
        *(float4*)&normed[o] = on;
        *(float4*)&a_eff[o]  = oa;
    }
}

// ---------------- K2: per-chunk local scan (h0=0) + chunk decay product ----------------
__global__ __launch_bounds__(256)
void scan_chunks(const float* __restrict__ a_eff, const float* __restrict__ nx,
                 float* __restrict__ Ach, float* __restrict__ Hch)
{
    const int idx = blockIdx.x * 256 + threadIdx.x;   // over NB*NCH*NW
    const int w  = idx & (NW - 1);
    const int bc = idx >> 10;                          // b*NCH + c
    const int c  = bc & (NCH - 1);
    const int b  = bc >> 6;
    size_t base = ((size_t)b * NT + (size_t)c * CHUNK) * NW + w;
    float A = 1.0f, hsum = 0.0f;
    #pragma unroll 8
    for (int t = 0; t < CHUNK; ++t) {
        const float a = a_eff[base];
        const float v = nx[base];
        A *= a;
        hsum = fmaf(a, hsum, v);
        base += NW;
    }
    Ach[(size_t)bc * NW + w] = A;
    Hch[(size_t)bc * NW + w] = hsum;
}

// ---------------- K3: inter-chunk scan per channel (exclusive: chunk-start h) ----------------
__global__ __launch_bounds__(256)
void scan_tops(const float* __restrict__ Ach, const float* __restrict__ Hch,
               float* __restrict__ Hst)
{
    const int idx = blockIdx.x * 256 + threadIdx.x;   // over NB*NW
    const int w = idx & (NW - 1);
    const int b = idx >> 10;
    float hh = 0.0f;
    #pragma unroll
    for (int c = 0; c < NCH; ++c) {
        const size_t o = ((size_t)b * NCH + c) * NW + w;
        Hst[o] = hh;
        hh = fmaf(Ach[o], hh, Hch[o]);
    }
}

// ---------------- K4: replay each chunk with correct initial h, write h in-place ----------------
__global__ __launch_bounds__(256)
void scan_apply(const float* __restrict__ a_eff, const float* __restrict__ Hst,
                float* __restrict__ out)
{
    const int idx = blockIdx.x * 256 + threadIdx.x;   // over NB*NCH*NW
    const int w  = idx & (NW - 1);
    const int bc = idx >> 10;
    const int c  = bc & (NCH - 1);
    const int b  = bc >> 6;
    size_t base = ((size_t)b * NT + (size_t)c * CHUNK) * NW + w;
    float hh = Hst[(size_t)bc * NW + w];
    #pragma unroll 8
    for (int t = 0; t < CHUNK; ++t) {
        const float a = a_eff[base];
        const float v = out[base];    // normed_x
        hh = fmaf(a, hh, v);
        out[base] = hh;               // same address, same thread: safe
        base += NW;
    }
}

extern "C" void kernel_launch(void* const* d_in, const int* in_sizes, int n_in,
                              void* d_out, int out_size, void* d_ws, size_t ws_size,
                              hipStream_t stream)
{
    (void)in_sizes; (void)n_in; (void)out_size; (void)ws_size;
    const float* x    = (const float*)d_in[0];
    const int*   seg  = (const int*)  d_in[1];
    const float* ap   = (const float*)d_in[2];
    const float* w_in = (const float*)d_in[3];
    const float* b_in = (const float*)d_in[4];
    const float* w_a  = (const float*)d_in[5];
    const float* b_a  = (const float*)d_in[6];
    float* out = (float*)d_out;

    // workspace layout: a_eff [B*T*W] fp32 (64MB), then 3x [B*NCH*W] fp32 (1MB each)
    float* a_eff = (float*)d_ws;
    float* Ach = a_eff + (size_t)NB * NT * NW;
    float* Hch = Ach + (size_t)NB * NCH * NW;
    float* Hst = Hch + (size_t)NB * NCH * NW;

    dim3 g1(NH, (NB * NT) / ROWS);
    gates_kernel<<<g1, 256, 0, stream>>>(x, seg, ap, w_in, b_in, w_a, b_a, a_eff, out);
    scan_chunks<<<(NB * NCH * NW) / 256, 256, 0, stream>>>(a_eff, out, Ach, Hch);
    scan_tops<<<(NB * NW) / 256, 256, 0, stream>>>(Ach, Hch, Hst);
    scan_apply<<<(NB * NCH * NW) / 256, 256, 0, stream>>>(a_eff, Hst, out);
}

// Round 2
// 246.594 us; speedup vs baseline: 1.3990x; 1.3990x over previous
//
#include <hip/hip_runtime.h>
#include <math.h>

// RG-LRU: B=4, T=4096, W=1024, H=8, BW=128
#define NB 4
#define NT 4096
#define NW 1024
#define NH 8
#define CHUNK 64
#define NCH 64          // NT / CHUNK

typedef __attribute__((ext_vector_type(8))) short short8;
typedef __attribute__((ext_vector_type(4))) float f32x4;

__device__ __forceinline__ short bf16rne(float f) {
    unsigned u = __float_as_uint(f);
    u += 0x7fffu + ((u >> 16) & 1u);      // round-to-nearest-even
    return (short)(u >> 16);
}
__device__ __forceinline__ float bf16tof(short h) {
    return __uint_as_float(((unsigned)(unsigned short)h) << 16);
}

// ---------------- K0: convert w_in/w_a to frag-major bf16 hi/lo ----------------
// dst index: ((((h*2+g)*4+ks)*8 + ntg)*64 + lane)*8 + jj
//   where i (input dim) = ks*32 + quad*8 + jj, lane = quad*16 + (j&15), ntg = j>>4
__global__ __launch_bounds__(256)
void k0_wfrag(const float* __restrict__ w_in, const float* __restrict__ w_a,
              short* __restrict__ wfH, short* __restrict__ wfL)
{
    int idx = blockIdx.x * 256 + threadIdx.x;   // over 2*8*128*32 = 65536
    int j4 = (idx & 31) * 4;
    int i  = (idx >> 5) & 127;
    int h  = (idx >> 12) & 7;
    int g  = idx >> 15;
    const float* w = g ? w_a : w_in;
    float4 v = *(const float4*)&w[((size_t)h * 128 + i) * 128 + j4];
    const float vf[4] = {v.x, v.y, v.z, v.w};
    const int ks = i >> 5, q = (i >> 3) & 3, jj = i & 7;
    #pragma unroll
    for (int d = 0; d < 4; ++d) {
        int j = j4 + d;
        int lane = q * 16 + (j & 15);
        int ntg = j >> 4;
        size_t dst = ((size_t)(((h * 2 + g) * 4 + ks) * 8 + ntg) * 64 + lane) * 8 + jj;
        short hb = bf16rne(vf[d]);
        wfH[dst] = hb;
        wfL[dst] = bf16rne(vf[d] - bf16tof(hb));
    }
}

// ---------------- K1: MFMA gates + in-register chunk-local scan ----------------
// grid (NH, NB*NCH), block 256 (4 waves). Block tile: 64 t (one chunk) x 128 w (one head).
// Waves split N: wave -> 2 n-tiles of 16 cols. 3-pass bf16-split MFMA for fp32-level accuracy.
// Outputs: P (cumulative decay within chunk), localh (scan with h0=0) -> d_out,
//          chunk tops (P63, lh63) for the inter-chunk scan.
__global__ __launch_bounds__(256)
void k1_gates_scan(const float* __restrict__ x, const int* __restrict__ seg,
                   const float* __restrict__ a_param,
                   const float* __restrict__ b_in, const float* __restrict__ b_a,
                   const short* __restrict__ wfH, const short* __restrict__ wfL,
                   float* __restrict__ P, float* __restrict__ out,
                   float* __restrict__ Atop, float* __restrict__ Htop)
{
    __shared__ float sP[16][132];   // pad 132: 2-way (free) bank aliasing, 16B-aligned rows
    __shared__ float sH[16][132];

    const int h   = blockIdx.x;
    const int bc  = blockIdx.y;
    const int b   = bc >> 6, c = bc & 63;
    const int tid = threadIdx.x;
    const int wave = tid >> 6, lane = tid & 63;
    const int quad = lane >> 4, m = lane & 15;
    const int row0 = b * NT + c * CHUNK;        // global row into [B*T]
    const int ntg0 = wave * 2;

    f32x4 acc[2][2][4];  // [gate][nt][mt]
    #pragma unroll
    for (int g = 0; g < 2; ++g)
        #pragma unroll
        for (int nt = 0; nt < 2; ++nt)
            #pragma unroll
            for (int mt = 0; mt < 4; ++mt)
                acc[g][nt][mt] = (f32x4){0.f, 0.f, 0.f, 0.f};

    // ---- MFMA main loop over K ----
    #pragma unroll
    for (int ks = 0; ks < 4; ++ks) {
        short8 ah[4], al[4];
        #pragma unroll
        for (int mt = 0; mt < 4; ++mt) {
            const float* px = x + (size_t)(row0 + mt * 16 + m) * NW + h * 128 + ks * 32 + quad * 8;
            float4 u0 = *(const float4*)px;
            float4 u1 = *(const float4*)(px + 4);
            const float uf[8] = {u0.x, u0.y, u0.z, u0.w, u1.x, u1.y, u1.z, u1.w};
            short8 hh, ll;
            #pragma unroll
            for (int j = 0; j < 8; ++j) {
                short hb = bf16rne(uf[j]);
                hh[j] = hb;
                ll[j] = bf16rne(uf[j] - bf16tof(hb));
            }
            ah[mt] = hh; al[mt] = ll;
        }
        #pragma unroll
        for (int g = 0; g < 2; ++g) {
            #pragma unroll
            for (int nt = 0; nt < 2; ++nt) {
                const size_t fo = ((size_t)(((h * 2 + g) * 4 + ks) * 8 + (ntg0 + nt)) * 64 + lane) * 8;
                short8 bh = *(const short8*)(wfH + fo);
                short8 bl = *(const short8*)(wfL + fo);
                #pragma unroll
                for (int mt = 0; mt < 4; ++mt) {
                    acc[g][nt][mt] = __builtin_amdgcn_mfma_f32_16x16x32_bf16(ah[mt], bh, acc[g][nt][mt], 0, 0, 0);
                    acc[g][nt][mt] = __builtin_amdgcn_mfma_f32_16x16x32_bf16(ah[mt], bl, acc[g][nt][mt], 0, 0, 0);
                    acc[g][nt][mt] = __builtin_amdgcn_mfma_f32_16x16x32_bf16(al[mt], bh, acc[g][nt][mt], 0, 0, 0);
                }
            }
        }
    }

    // ---- per-column parameters ----
    float bi[2], ba[2], sp[2];
    #pragma unroll
    for (int nt = 0; nt < 2; ++nt) {
        int colg = h * 128 + (ntg0 + nt) * 16 + m;
        bi[nt] = b_in[colg];
        ba[nt] = b_a[colg];
        sp[nt] = log1pf(expf(a_param[colg]));   // softplus, a_param < 0
    }

    // ---- epilogue + in-register scan (C layout: row = quad*4+reg, col = lane&15) ----
    float cA[2] = {1.f, 1.f}, cH[2] = {0.f, 0.f};   // carry across m-tiles, per nt
    for (int mt = 0; mt < 4; ++mt) {
        #pragma unroll
        for (int nt = 0; nt < 2; ++nt) {
            float av[4], nx[4];
            #pragma unroll
            for (int r = 0; r < 4; ++r) {
                float zx = acc[0][nt][mt][r] + bi[nt];
                float za = acc[1][nt][mt][r] + ba[nt];
                float gx = 1.f / (1.f + expf(-zx));
                float ga = 1.f / (1.f + expf(-za));
                float a  = expf(-8.f * ga * sp[nt]);
                float mult = sqrtf(fmaxf(1.f - a * a, 0.f));
                int rowi = mt * 16 + quad * 4 + r;
                float xv = x[(size_t)(row0 + rowi) * NW + h * 128 + (ntg0 + nt) * 16 + m];
                int sv = seg[row0 + rowi];
                av[r] = (sv == 0) ? 0.f : a;
                nx[r] = xv * gx * mult;
            }
            // lane-local inclusive scan over 4 consecutive t
            float lP[4], lH[4];
            lP[0] = av[0]; lH[0] = nx[0];
            #pragma unroll
            for (int r = 1; r < 4; ++r) {
                lP[r] = lP[r - 1] * av[r];
                lH[r] = fmaf(av[r], lH[r - 1], nx[r]);
            }
            // inclusive scan of quad totals across the 4 quads (same column = same lane&15)
            float iA = lP[3], iH = lH[3];
            float uA = __shfl_up(iA, 16), uH = __shfl_up(iH, 16);
            if (quad >= 1) { iH = fmaf(iA, uH, iH); iA = uA * iA; }
            uA = __shfl_up(iA, 32); uH = __shfl_up(iH, 32);
            if (quad >= 2) { iH = fmaf(iA, uH, iH); iA = uA * iA; }
            // exclusive prefix for this quad
            float eA = __shfl_up(iA, 16), eH = __shfl_up(iH, 16);
            if (quad == 0) { eA = 1.f; eH = 0.f; }
            // total over all 16 t of this m-tile (from quad 3's inclusive value)
            float mAt = __shfl(iA, 48 + m), mHt = __shfl(iH, 48 + m);
            // prefix = carry ∘ quad-exclusive
            float pA = cA[nt] * eA;
            float pH = fmaf(eA, cH[nt], eH);
            // carry update: carry ∘ mtile-total
            cH[nt] = fmaf(mAt, cH[nt], mHt);
            cA[nt] = cA[nt] * mAt;
            // finals -> LDS (for coalesced transposed store)
            int colw = (ntg0 + nt) * 16 + m;
            #pragma unroll
            for (int r = 0; r < 4; ++r) {
                float Pf = pA * lP[r];
                float Hf = fmaf(lP[r], pH, lH[r]);
                sP[quad * 4 + r][colw] = Pf;
                sH[quad * 4 + r][colw] = Hf;
            }
        }
        __syncthreads();
        // drain: 16 rows x 128 cols, coalesced float4 stores
        #pragma unroll
        for (int pass = 0; pass < 2; ++pass) {
            int row = pass * 8 + (tid >> 5);
            int c4  = tid & 31;
            float4 vP = *(float4*)&sP[row][c4 * 4];
            float4 vH = *(float4*)&sH[row][c4 * 4];
            size_t go = (size_t)(row0 + mt * 16 + row) * NW + h * 128 + c4 * 4;
            *(float4*)&P[go]   = vP;
            *(float4*)&out[go] = vH;
            if (mt == 3 && row == 15) {   // chunk tops for inter-chunk scan
                size_t to = (size_t)bc * NW + h * 128 + c4 * 4;
                *(float4*)&Atop[to] = vP;
                *(float4*)&Htop[to] = vH;
            }
        }
        __syncthreads();
    }
}

// ---------------- K3: inter-chunk exclusive scan; Hst written in-place into Atop ----------------
__global__ __launch_bounds__(256)
void k3_tops(float* __restrict__ Atop, const float* __restrict__ Htop)
{
    int idx = blockIdx.x * 256 + threadIdx.x;   // over NB*NW
    int w = idx & (NW - 1);
    int b = idx >> 10;
    float hh = 0.f;
    #pragma unroll
    for (int cc = 0; cc < NCH; ++cc) {
        size_t o = ((size_t)(b * NCH + cc)) * NW + w;
        float A = Atop[o];
        float H = Htop[o];
        Atop[o] = hh;                // exclusive: state entering chunk cc
        hh = fmaf(A, hh, H);
    }
}

// ---------------- K4: elementwise fix-up  out = localh + P * h_start ----------------
__global__ __launch_bounds__(256)
void k4_apply(const float* __restrict__ P, const float* __restrict__ Hst,
              float* __restrict__ out)
{
    int idx = blockIdx.x * 256 + threadIdx.x;   // over NB*NT*NW/4
    int row = idx >> 8;                          // b*NT + t
    int w4  = (idx & 255) * 4;
    int c = (row & (NT - 1)) >> 6;
    int b = row >> 12;
    size_t go = (size_t)row * NW + w4;
    float4 p  = *(const float4*)&P[go];
    float4 lh = *(const float4*)&out[go];
    float4 hs = *(const float4*)&Hst[((size_t)(b * NCH + c)) * NW + w4];
    float4 o;
    o.x = fmaf(p.x, hs.x, lh.x);
    o.y = fmaf(p.y, hs.y, lh.y);
    o.z = fmaf(p.z, hs.z, lh.z);
    o.w = fmaf(p.w, hs.w, lh.w);
    *(float4*)&out[go] = o;
}

extern "C" void kernel_launch(void* const* d_in, const int* in_sizes, int n_in,
                              void* d_out, int out_size, void* d_ws, size_t ws_size,
                              hipStream_t stream)
{
    (void)in_sizes; (void)n_in; (void)out_size; (void)ws_size;
    const float* x    = (const float*)d_in[0];
    const int*   seg  = (const int*)  d_in[1];
    const float* ap   = (const float*)d_in[2];
    const float* w_in = (const float*)d_in[3];
    const float* b_in = (const float*)d_in[4];
    const float* w_a  = (const float*)d_in[5];
    const float* b_a  = (const float*)d_in[6];
    float* out = (float*)d_out;

    // ws layout (67 MiB total, same footprint as the passing round-1 kernel):
    //   P     : NB*NT*NW fp32          = 64 MiB
    //   Atop  : NB*NCH*NW fp32         =  1 MiB   (becomes Hst after K3)
    //   Htop  : NB*NCH*NW fp32         =  1 MiB
    //   wfH/L : 2*8*128*128 bf16 each  =  1 MiB
    float* Pws  = (float*)d_ws;
    float* Atop = Pws + (size_t)NB * NT * NW;
    float* Htop = Atop + (size_t)NB * NCH * NW;
    short* wfH  = (short*)(Htop + (size_t)NB * NCH * NW);
    short* wfL  = wfH + (size_t)2 * NH * 128 * 128;

    k0_wfrag<<<256, 256, 0, stream>>>(w_in, w_a, wfH, wfL);
    dim3 g1(NH, NB * NCH);
    k1_gates_scan<<<g1, 256, 0, stream>>>(x, seg, ap, b_in, b_a, wfH, wfL,
                                          Pws, out, Atop, Htop);
    k3_tops<<<(NB * NW) / 256, 256, 0, stream>>>(Atop, Htop);
    k4_apply<<<((size_t)NB * NT * NW / 4) / 256, 256, 0, stream>>>(Pws, Atop, out);
}